// Round 8
// baseline (333.694 us; speedup 1.0000x reference)
//
#include <hip/hip_runtime.h>
#include <hip/hip_bf16.h>
#include <cstdint>
#include <cstddef>

typedef unsigned short u16;
typedef __attribute__((ext_vector_type(4))) unsigned short u16x4;
typedef __attribute__((ext_vector_type(8))) unsigned short u16x8;
typedef __attribute__((ext_vector_type(8))) __bf16 bf16x8;
typedef __attribute__((ext_vector_type(4))) float f32x4;

#define MFMA16(a, b, c) __builtin_amdgcn_mfma_f32_16x16x32_bf16((a), (b), (c), 0, 0, 0)

__device__ __forceinline__ u16 f2bf(float f) {
  uint32_t u = __builtin_bit_cast(uint32_t, f);
  u += 0x7FFFu + ((u >> 16) & 1u);
  return (u16)(u >> 16);
}
__device__ __forceinline__ float bf2f(u16 h) {
  return __builtin_bit_cast(float, (uint32_t)h << 16);
}

typedef const __attribute__((address_space(1))) void gv_t;
typedef __attribute__((address_space(3))) void lv_t;
__device__ __forceinline__ void gload16(const void* g, void* l) {
  __builtin_amdgcn_global_load_lds((gv_t*)g, (lv_t*)l, 16, 0, 0);
}

// ---------------- f32 -> bf16 convert (vectorized) ----------------
__global__ void cvt_f32_to_bf16(const float* __restrict__ in, u16* __restrict__ out, int n4) {
  int i = blockIdx.x * 256 + threadIdx.x;
  if (i >= n4) return;
  float4 v = ((const float4*)in)[i];
  u16x4 o;
  o[0] = f2bf(v.x); o[1] = f2bf(v.y); o[2] = f2bf(v.z); o[3] = f2bf(v.w);
  ((u16x4*)out)[i] = o;
}

// ------------- transpose + convert x4: W[2048][2048] f32 -> Wt bf16 [N][K], z picks W -------------
__global__ void transpose_cvt4(const float* __restrict__ w0, const float* __restrict__ w1,
                               const float* __restrict__ w2, const float* __restrict__ w3,
                               u16* __restrict__ outbase) {
  __shared__ float tile[32][33];
  const int z = blockIdx.z;
  const float* in = (z == 0) ? w0 : (z == 1) ? w1 : (z == 2) ? w2 : w3;
  u16* out = outbase + (size_t)z * 4194304;  // 2048*2048 each
  const int bx = blockIdx.x, by = blockIdx.y;
  const int tx = threadIdx.x, ty = threadIdx.y;
#pragma unroll
  for (int i = 0; i < 32; i += 8)
    tile[ty + i][tx] = in[(size_t)(by * 32 + ty + i) * 2048 + bx * 32 + tx];
  __syncthreads();
#pragma unroll
  for (int i = 0; i < 32; i += 8)
    out[(size_t)(bx * 32 + ty + i) * 2048 + by * 32 + tx] = f2bf(tile[tx][ty + i]);
}

// ------------- per-head transpose of V: bf16 [B*S][H*dk] -> VT [B,H,dk,S] -------------
__global__ void vtrans(const u16* __restrict__ in, u16* __restrict__ out) {
  __shared__ u16 tile[32][34];
  const int bx = blockIdx.x, by = blockIdx.y;
  const int tx = threadIdx.x, ty = threadIdx.y;
#pragma unroll
  for (int i = 0; i < 32; i += 8)
    tile[ty + i][tx] = in[(size_t)(by * 32 + ty + i) * 2048 + bx * 32 + tx];
  __syncthreads();
#pragma unroll
  for (int i = 0; i < 32; i += 8) {
    const int c = bx * 32 + ty + i;      // 0..2047 = h*128 + d
    const int token = by * 32 + tx;      // 0..4095 = b*2048 + s
    out[(((size_t)(token >> 11) * 16 + (c >> 7)) * 128 + (c & 127)) * 2048 + (token & 2047)] =
        tile[tx][ty + i];
  }
}

// ============ merged-phase GEMM: C[M,*] = A[M,2048] * Bt[*,2048]^T ============
// BM=256, BN=128, BK=64, 512 threads (8 waves: 4M x 2N, per-wave 64x64).
// 3-deep LDS pipeline, counted vmcnt(6), ONE barrier per K-tile, 16 ds_reads up-front,
// single 32-MFMA run under setprio. T2 swizzle both-sides.
// MODE 1: f32 C [M][2048].  MODE 2: bf16 QKV split + FUSED RoPE on Q/K sections.
template <int MODE>
__global__ __launch_bounds__(512, 1) void gemm8(const u16* __restrict__ A,
                                                const u16* __restrict__ Bt,
                                                void* __restrict__ Cv,
                                                const int* __restrict__ pos, int nbn) {
  constexpr int K = 2048;
  __shared__ __align__(16) u16 lds[73728];  // 3 x (A 32KB + B 16KB) = 144KB
  const int tid = threadIdx.x, lane = tid & 63;
  const int lo16 = lane & 15, hi = lane >> 4;
  const int wid = tid >> 6;
  const int wr = wid >> 1, wc = wid & 1;

  // XCD-aware bijective swizzle (gridDim.x % 8 == 0 at both call sites)
  const int per = (int)gridDim.x >> 3;
  const int wg = ((int)blockIdx.x & 7) * per + ((int)blockIdx.x >> 3);
  const int bn = (wg % nbn) * 128;
  const int bm = (wg / nbn) * 256;

  // staging: round = 64 rows x 64 cols, thread -> (row=tid>>3, 16B slot=tid&7)
  const int srow = tid >> 3;
  const int scol = ((tid & 7) ^ (srow & 7)) * 8;  // pre-swizzled source col (elements)
  const u16* Arow = A + (size_t)(bm + srow) * K + scol;
  const u16* Brow = Bt + (size_t)(bn + srow) * K + scol;
  char* dstbase = (char*)lds + tid * 16;

#define STG_A(qb_, t_, r_) \
  gload16(Arow + (size_t)(r_) * 64 * K + (t_) * 64, dstbase + (qb_) * 49152 + (r_) * 8192)
#define STG_B(qb_, t_, r_) \
  gload16(Brow + (size_t)(r_) * 64 * K + (t_) * 64, dstbase + (qb_) * 49152 + 32768 + (r_) * 8192)

  f32x4 acc[4][4];
  const f32x4 z4 = {0.f, 0.f, 0.f, 0.f};
#pragma unroll
  for (int m = 0; m < 4; ++m)
#pragma unroll
    for (int n = 0; n < 4; ++n) acc[m][n] = z4;

  // ds_read address components (bytes)
  const int xork = lo16 & 7;
  const int aRow = (wr * 64 + lo16) * 128;          // + m*2048
  const int bRow = 32768 + (wc * 64 + lo16) * 128;  // + n*2048
  const int x0 = ((hi ^ xork)) << 4;                // kk=0 slot
  const int x1 = (((4 + hi) ^ xork)) << 4;          // kk=1 slot

  // prologue: stage tiles 0 and 1
  STG_A(0, 0, 0); STG_A(0, 0, 1); STG_A(0, 0, 2); STG_A(0, 0, 3);
  STG_B(0, 0, 0); STG_B(0, 0, 1);
  STG_A(1, 1, 0); STG_A(1, 1, 1); STG_A(1, 1, 2); STG_A(1, 1, 3);
  STG_B(1, 1, 0); STG_B(1, 1, 1);

  int q = 0;
  for (int t = 0; t < 32; ++t) {
    if (t < 31) {
      asm volatile("s_waitcnt vmcnt(6)" ::: "memory");  // own tile-t loads landed
    } else {
      asm volatile("s_waitcnt vmcnt(0)" ::: "memory");
    }
    __builtin_amdgcn_s_barrier();          // all waves' tile-t loads landed
    __builtin_amdgcn_sched_barrier(0);     // nothing hoists above the barrier
    const char* Aq = (const char*)lds + q * 49152;
    const int q2 = (q == 0) ? 2 : q - 1;   // buffer for tile t+2

    bf16x8 a0[4], b0[4], a1[4], b1[4];
#pragma unroll
    for (int m = 0; m < 4; ++m) a0[m] = *(const bf16x8*)(Aq + aRow + m * 2048 + x0);
#pragma unroll
    for (int n = 0; n < 4; ++n) b0[n] = *(const bf16x8*)(Aq + bRow + n * 2048 + x0);
#pragma unroll
    for (int m = 0; m < 4; ++m) a1[m] = *(const bf16x8*)(Aq + aRow + m * 2048 + x1);
#pragma unroll
    for (int n = 0; n < 4; ++n) b1[n] = *(const bf16x8*)(Aq + bRow + n * 2048 + x1);

    if (t < 30) {
      STG_A(q2, t + 2, 0); STG_A(q2, t + 2, 1); STG_A(q2, t + 2, 2); STG_A(q2, t + 2, 3);
      STG_B(q2, t + 2, 0); STG_B(q2, t + 2, 1);
    }

    __builtin_amdgcn_s_setprio(1);
#pragma unroll
    for (int m = 0; m < 4; ++m)
#pragma unroll
      for (int n = 0; n < 4; ++n) acc[m][n] = MFMA16(a0[m], b0[n], acc[m][n]);
#pragma unroll
    for (int m = 0; m < 4; ++m)
#pragma unroll
      for (int n = 0; n < 4; ++n) acc[m][n] = MFMA16(a1[m], b1[n], acc[m][n]);
    __builtin_amdgcn_s_setprio(0);
    q = (q == 2) ? 0 : q + 1;
  }
#undef STG_A
#undef STG_B

  // ---- epilogue ----
  if constexpr (MODE == 2) {
    const int sect = bn >> 11;  // 0=Q, 1=K, 2=V (buffers 16MB apart = 8388608 u16)
    u16* Cq = (u16*)Cv + (size_t)sect * 8388608;
    const int cb = (bn & 2047) + wc * 64;
    if (sect < 2) {
      // fused RoPE: lane pairs (lo16^1) hold the (even,odd) column pair
      const float qsc = (sect == 0) ? 0.08838834764831845f : 1.0f;
#pragma unroll
      for (int n = 0; n < 4; ++n) {
        const int c = cb + n * 16 + lo16;
        const float freq = exp2f((float)((c & 127) >> 1) * -0.2076205059304601f);
        const float sgn = (c & 1) ? 1.f : -1.f;
#pragma unroll
        for (int m = 0; m < 4; ++m) {
          const int row = bm + wr * 64 + m * 16 + hi * 4;
#pragma unroll
          for (int r = 0; r < 4; ++r) {
            const float p = (float)pos[row + r];
            float sn, cs;
            sincosf(p * freq, &sn, &cs);
            const float v = acc[m][n][r];
            const float pv = __shfl_xor(v, 1);
            Cq[(size_t)(row + r) * 2048 + c] = f2bf((v * cs + sgn * pv * sn) * qsc);
          }
        }
      }
    } else {
#pragma unroll
      for (int m = 0; m < 4; ++m)
#pragma unroll
        for (int n = 0; n < 4; ++n)
#pragma unroll
          for (int r = 0; r < 4; ++r)
            Cq[(size_t)(bm + wr * 64 + m * 16 + hi * 4 + r) * 2048 + cb + n * 16 + lo16] =
                f2bf(acc[m][n][r]);
    }
  } else {
    float* C = (float*)Cv;
    const int cb = bn + wc * 64;
#pragma unroll
    for (int m = 0; m < 4; ++m)
#pragma unroll
      for (int n = 0; n < 4; ++n)
#pragma unroll
        for (int r = 0; r < 4; ++r)
          C[(size_t)(bm + wr * 64 + m * 16 + hi * 4 + r) * 2048 + cb + n * 16 + lo16] =
              acc[m][n][r];
  }
}

// ------------- causal flash attention v4: QTILE=64 (4 waves x 16 rows), KVBLK=64 -------------
// Each block processes TWO complementary q-tiles (31-pairid, then pairid) => exactly 33
// KV-steps per block, balance independent of block->CU mapping. Double-buffered K/V staging.
__global__ __launch_bounds__(256, 2) void flash_attn4(const u16* __restrict__ Qb,
                                                      const u16* __restrict__ Kb,
                                                      const u16* __restrict__ VT,
                                                      u16* __restrict__ Ob) {
  constexpr int S = 2048, HD = 2048;
  const int g = (int)blockIdx.x;
  const int xcd = g & 7, slot = g >> 3;      // 64 slots per XCD
  const int bh = xcd * 4 + (slot & 3);       // 4 heads per XCD (K/V ~2MB -> L2 resident)
  const int pairid = slot >> 2;              // 0..15
  const int b = bh >> 4, h = bh & 15;
  const int tid = threadIdx.x, lane = tid & 63, wid = tid >> 6;

  __shared__ u16 Ks[2][64 * 128];   // [kv][d] swizzled, double-buffered (32KB)
  __shared__ u16 Vs[2][128 * 64];   // [d][kv] swizzled, double-buffered (32KB)
  __shared__ u16 Ps[4][16 * 64];    // per-wave P [q][kv], swizzled (8KB)

  const size_t base = (size_t)b * S * HD + (size_t)h * 128;
  const u16* Qp = Qb + base;
  const u16* Kp = Kb + base;
  const u16* VTp = VT + (size_t)bh * 128 * S;
  u16* Op = Ob + base;

  const f32x4 z4 = {0.f, 0.f, 0.f, 0.f};
  const int kKv = (lane >> 4);
  const int kC16 = (lane & 15);
  const int vD = (lane >> 3);
  const int vC16 = (lane & 7);

#define STAGE(pb, kv0_)                                                                   \
  {                                                                                       \
    _Pragma("unroll") for (int c = 0; c < 4; ++c) {                                       \
      const int ch = wid * 4 + c;                                                         \
      {                                                                                   \
        const int kv = ch * 4 + kKv;                                                      \
        const int c16 = kC16 ^ (kv & 7);                                                  \
        gload16(Kp + (size_t)((kv0_) + kv) * HD + c16 * 8, (char*)Ks[pb] + ch * 1024);    \
      }                                                                                   \
      {                                                                                   \
        const int d = ch * 8 + vD;                                                        \
        const int c16 = vC16 ^ (d & 7);                                                   \
        gload16(VTp + (size_t)d * S + (kv0_) + c16 * 8, (char*)Vs[pb] + ch * 1024);       \
      }                                                                                   \
    }                                                                                     \
  }

#pragma unroll
  for (int half = 0; half < 2; ++half) {
    const int qt = half ? pairid : 31 - pairid;  // heavy tile first
    const int q0 = qt * 64;

    bf16x8 qf[4];
    {
      const int qr = q0 + wid * 16 + (lane & 15);
      const int kc = (lane >> 4) * 8;
#pragma unroll
      for (int kb = 0; kb < 4; ++kb)
        qf[kb] = *(const bf16x8*)(Qp + (size_t)qr * HD + kb * 32 + kc);
    }

    f32x4 accO[8];
#pragma unroll
    for (int d = 0; d < 8; ++d) accO[d] = z4;
    float m_r[4] = {-INFINITY, -INFINITY, -INFINITY, -INFINITY};
    float l_r[4] = {0.f, 0.f, 0.f, 0.f};

    STAGE(0, 0);
    __syncthreads();  // buffer 0 ready (drains vmcnt)

    for (int t = 0; t <= qt; ++t) {
      const int cur = t & 1;
      const int kv0 = t * 64;
      if (t < qt) STAGE(cur ^ 1, kv0 + 64);  // prefetch next tile into other buffer

      const u16* Ksc = Ks[cur];
      const u16* Vsc = Vs[cur];
      f32x4 accS[4];
#pragma unroll
      for (int nb = 0; nb < 4; ++nb) accS[nb] = z4;

      // ---- S = Q K^T ----
      __builtin_amdgcn_s_setprio(1);
#pragma unroll
      for (int nb = 0; nb < 4; ++nb) {
        const int kv = nb * 16 + (lane & 15);
#pragma unroll
        for (int kb = 0; kb < 4; ++kb) {
          const int c16 = (kb * 4 + (lane >> 4)) ^ (kv & 7);
          bf16x8 kf = *(const bf16x8*)((char*)Ksc + kv * 256 + c16 * 16);
          accS[nb] = MFMA16(qf[kb], kf, accS[nb]);
        }
      }
      __builtin_amdgcn_s_setprio(0);

      // ---- causal mask (diagonal step only) ----
      if (t == qt) {
#pragma unroll
        for (int nb = 0; nb < 4; ++nb) {
          const int kv = kv0 + nb * 16 + (lane & 15);
          const int qrow = q0 + wid * 16 + (lane >> 4) * 4;
#pragma unroll
          for (int j = 0; j < 4; ++j)
            if (kv > qrow + j) accS[nb][j] = -INFINITY;
        }
      }

      // ---- online softmax (row = (lane>>4)*4+j) + P write ----
      u16* Pw = &Ps[wid][0];
#pragma unroll
      for (int j = 0; j < 4; ++j) {
        float mx = fmaxf(fmaxf(accS[0][j], accS[1][j]), fmaxf(accS[2][j], accS[3][j]));
#pragma unroll
        for (int off = 1; off < 16; off <<= 1) mx = fmaxf(mx, __shfl_xor(mx, off));
        const float mn = fmaxf(m_r[j], mx);
        const float sc = __expf(m_r[j] - mn);
        m_r[j] = mn;
        float s = 0.f;
#pragma unroll
        for (int nb = 0; nb < 4; ++nb) {
          const float p = __expf(accS[nb][j] - mn);
          accS[nb][j] = p;
          s += p;
        }
#pragma unroll
        for (int off = 1; off < 16; off <<= 1) s += __shfl_xor(s, off);
        l_r[j] = l_r[j] * sc + s;
#pragma unroll
        for (int db = 0; db < 8; ++db) accO[db][j] *= sc;
        const int ql = (lane >> 4) * 4 + j;
#pragma unroll
        for (int nb = 0; nb < 4; ++nb) {
          const int col = nb * 16 + (lane & 15);
          const int byteoff = ql * 128 + ((((col >> 3) ^ (ql & 7))) << 4) + (col & 7) * 2;
          *(u16*)((char*)Pw + byteoff) = f2bf(accS[nb][j]);
        }
      }

      // ---- O += P V ----
#pragma unroll
      for (int kb2 = 0; kb2 < 2; ++kb2) {
        const int ql = lane & 15;
        const int c16a = (kb2 * 4 + (lane >> 4)) ^ (ql & 7);
        bf16x8 pa = *(const bf16x8*)((char*)Pw + ql * 128 + c16a * 16);
        __builtin_amdgcn_s_setprio(1);
#pragma unroll
        for (int db = 0; db < 8; ++db) {
          const int d = db * 16 + (lane & 15);
          const int c16 = (kb2 * 4 + (lane >> 4)) ^ (d & 7);
          bf16x8 vf = *(const bf16x8*)((char*)Vsc + d * 128 + c16 * 16);
          accO[db] = MFMA16(pa, vf, accO[db]);
        }
        __builtin_amdgcn_s_setprio(0);
      }
      __syncthreads();  // prefetch landed during compute; LDS reads of this step done
    }

    // ---- epilogue: normalize, store bf16 ----
    float inv[4];
#pragma unroll
    for (int j = 0; j < 4; ++j) inv[j] = 1.f / l_r[j];
#pragma unroll
    for (int db = 0; db < 8; ++db)
#pragma unroll
      for (int j = 0; j < 4; ++j) {
        const int row = q0 + wid * 16 + (lane >> 4) * 4 + j;
        Op[(size_t)row * HD + db * 16 + (lane & 15)] = f2bf(accO[db][j] * inv[j]);
      }
  }
#undef STAGE
}

extern "C" void kernel_launch(void* const* d_in, const int* in_sizes, int n_in,
                              void* d_out, int out_size, void* d_ws, size_t ws_size,
                              hipStream_t stream) {
  const float* x  = (const float*)d_in[0];
  const int*   tp = (const int*)d_in[1];
  const float* WQ = (const float*)d_in[2];
  const float* WK = (const float*)d_in[3];
  const float* WV = (const float*)d_in[4];
  const float* WO = (const float*)d_in[5];

  const size_t MB = 1024 * 1024;
  if (ws_size < 112 * MB) return;
  char* ws = (char*)d_ws;
  u16* xb  = (u16*)(ws + 0 * MB);
  u16* wqt = (u16*)(ws + 16 * MB);   // wqt/wkt/wvt/wot contiguous, 8MB each
  u16* wot = (u16*)(ws + 40 * MB);
  u16* Qb  = (u16*)(ws + 48 * MB);   // Qb/Kb/Vb contiguous, 16MB apart
  u16* Kb  = (u16*)(ws + 64 * MB);
  u16* Vb  = (u16*)(ws + 80 * MB);
  u16* Obf = (u16*)(ws + 96 * MB);
  u16* VTb = xb;  // V^T [B,H,dk,S] (xb dead after projections)

  cvt_f32_to_bf16<<<8192, 256, 0, stream>>>(x, xb, 2097152);
  {
    dim3 g(64, 64, 4), blk(32, 8);
    transpose_cvt4<<<g, blk, 0, stream>>>(WQ, WK, WV, WO, wqt);
  }
  // fused QKV projection + RoPE: [4096][2048] x [6144][2048]^T -> Qb|Kb|Vb
  gemm8<2><<<768, 512, 0, stream>>>(xb, wqt, (void*)Qb, tp, 48);

  {
    dim3 g(64, 128), blk(32, 8);
    vtrans<<<g, blk, 0, stream>>>(Vb, VTb);
  }
  flash_attn4<<<512, 256, 0, stream>>>(Qb, Kb, VTb, Obf);

  // output projection -> f32 d_out
  gemm8<1><<<256, 512, 0, stream>>>(Obf, wot, d_out, nullptr, 16);
}

// Round 9
// 264.440 us; speedup vs baseline: 1.2619x; 1.2619x over previous
//
#include <hip/hip_runtime.h>
#include <hip/hip_bf16.h>
#include <cstdint>
#include <cstddef>

typedef unsigned short u16;
typedef __attribute__((ext_vector_type(4))) unsigned short u16x4;
typedef __attribute__((ext_vector_type(8))) unsigned short u16x8;
typedef __attribute__((ext_vector_type(8))) __bf16 bf16x8;
typedef __attribute__((ext_vector_type(4))) float f32x4;

#define MFMA16(a, b, c) __builtin_amdgcn_mfma_f32_16x16x32_bf16((a), (b), (c), 0, 0, 0)

__device__ __forceinline__ u16 f2bf(float f) {
  uint32_t u = __builtin_bit_cast(uint32_t, f);
  u += 0x7FFFu + ((u >> 16) & 1u);
  return (u16)(u >> 16);
}
__device__ __forceinline__ float bf2f(u16 h) {
  return __builtin_bit_cast(float, (uint32_t)h << 16);
}

typedef const __attribute__((address_space(1))) void gv_t;
typedef __attribute__((address_space(3))) void lv_t;
__device__ __forceinline__ void gload16(const void* g, void* l) {
  __builtin_amdgcn_global_load_lds((gv_t*)g, (lv_t*)l, 16, 0, 0);
}

// ---------------- f32 -> bf16 convert (vectorized) ----------------
__global__ void cvt_f32_to_bf16(const float* __restrict__ in, u16* __restrict__ out, int n4) {
  int i = blockIdx.x * 256 + threadIdx.x;
  if (i >= n4) return;
  float4 v = ((const float4*)in)[i];
  u16x4 o;
  o[0] = f2bf(v.x); o[1] = f2bf(v.y); o[2] = f2bf(v.z); o[3] = f2bf(v.w);
  ((u16x4*)out)[i] = o;
}

// ------------- transpose + convert x4: W[2048][2048] f32 -> Wt bf16 [N][K], z picks W -------------
__global__ void transpose_cvt4(const float* __restrict__ w0, const float* __restrict__ w1,
                               const float* __restrict__ w2, const float* __restrict__ w3,
                               u16* __restrict__ outbase) {
  __shared__ float tile[32][33];
  const int z = blockIdx.z;
  const float* in = (z == 0) ? w0 : (z == 1) ? w1 : (z == 2) ? w2 : w3;
  u16* out = outbase + (size_t)z * 4194304;  // 2048*2048 each
  const int bx = blockIdx.x, by = blockIdx.y;
  const int tx = threadIdx.x, ty = threadIdx.y;
#pragma unroll
  for (int i = 0; i < 32; i += 8)
    tile[ty + i][tx] = in[(size_t)(by * 32 + ty + i) * 2048 + bx * 32 + tx];
  __syncthreads();
#pragma unroll
  for (int i = 0; i < 32; i += 8)
    out[(size_t)(bx * 32 + ty + i) * 2048 + by * 32 + tx] = f2bf(tile[tx][ty + i]);
}

// ------------- per-head transpose of V: bf16 [B*S][H*dk] -> VT [B,H,dk,S] -------------
__global__ void vtrans(const u16* __restrict__ in, u16* __restrict__ out) {
  __shared__ u16 tile[32][34];
  const int bx = blockIdx.x, by = blockIdx.y;
  const int tx = threadIdx.x, ty = threadIdx.y;
#pragma unroll
  for (int i = 0; i < 32; i += 8)
    tile[ty + i][tx] = in[(size_t)(by * 32 + ty + i) * 2048 + bx * 32 + tx];
  __syncthreads();
#pragma unroll
  for (int i = 0; i < 32; i += 8) {
    const int c = bx * 32 + ty + i;      // 0..2047 = h*128 + d
    const int token = by * 32 + tx;      // 0..4095 = b*2048 + s
    out[(((size_t)(token >> 11) * 16 + (c >> 7)) * 128 + (c & 127)) * 2048 + (token & 2047)] =
        tile[tx][ty + i];
  }
}

// ============ merged-phase GEMM: C[M,*] = A[M,2048] * Bt[*,2048]^T ============
// BM=256, BN=128, BK=64, 512 threads (8 waves: 4M x 2N, per-wave 64x64).
// 3-deep LDS pipeline, counted vmcnt(6), ONE barrier per K-tile, 16 ds_reads up-front,
// single 32-MFMA run under setprio. T2 swizzle both-sides.
// MODE 1: f32 C [M][2048].  MODE 2: bf16 QKV split + FUSED RoPE (no-scratch __sinf/__cosf).
template <int MODE>
__global__ __launch_bounds__(512, 1) void gemm8(const u16* __restrict__ A,
                                                const u16* __restrict__ Bt,
                                                void* __restrict__ Cv,
                                                const int* __restrict__ pos, int nbn) {
  constexpr int K = 2048;
  __shared__ __align__(16) u16 lds[73728];  // 3 x (A 32KB + B 16KB) = 144KB
  const int tid = threadIdx.x, lane = tid & 63;
  const int lo16 = lane & 15, hi = lane >> 4;
  const int wid = tid >> 6;
  const int wr = wid >> 1, wc = wid & 1;

  // XCD-aware bijective swizzle (gridDim.x % 8 == 0 at both call sites)
  const int per = (int)gridDim.x >> 3;
  const int wg = ((int)blockIdx.x & 7) * per + ((int)blockIdx.x >> 3);
  const int bn = (wg % nbn) * 128;
  const int bm = (wg / nbn) * 256;

  // staging: round = 64 rows x 64 cols, thread -> (row=tid>>3, 16B slot=tid&7)
  const int srow = tid >> 3;
  const int scol = ((tid & 7) ^ (srow & 7)) * 8;  // pre-swizzled source col (elements)
  const u16* Arow = A + (size_t)(bm + srow) * K + scol;
  const u16* Brow = Bt + (size_t)(bn + srow) * K + scol;
  char* dstbase = (char*)lds + tid * 16;

#define STG_A(qb_, t_, r_) \
  gload16(Arow + (size_t)(r_) * 64 * K + (t_) * 64, dstbase + (qb_) * 49152 + (r_) * 8192)
#define STG_B(qb_, t_, r_) \
  gload16(Brow + (size_t)(r_) * 64 * K + (t_) * 64, dstbase + (qb_) * 49152 + 32768 + (r_) * 8192)

  f32x4 acc[4][4];
  const f32x4 z4 = {0.f, 0.f, 0.f, 0.f};
#pragma unroll
  for (int m = 0; m < 4; ++m)
#pragma unroll
    for (int n = 0; n < 4; ++n) acc[m][n] = z4;

  // ds_read address components (bytes)
  const int xork = lo16 & 7;
  const int aRow = (wr * 64 + lo16) * 128;          // + m*2048
  const int bRow = 32768 + (wc * 64 + lo16) * 128;  // + n*2048
  const int x0 = ((hi ^ xork)) << 4;                // kk=0 slot
  const int x1 = (((4 + hi) ^ xork)) << 4;          // kk=1 slot

  // prologue: stage tiles 0 and 1
  STG_A(0, 0, 0); STG_A(0, 0, 1); STG_A(0, 0, 2); STG_A(0, 0, 3);
  STG_B(0, 0, 0); STG_B(0, 0, 1);
  STG_A(1, 1, 0); STG_A(1, 1, 1); STG_A(1, 1, 2); STG_A(1, 1, 3);
  STG_B(1, 1, 0); STG_B(1, 1, 1);

  int q = 0;
  for (int t = 0; t < 32; ++t) {
    if (t < 31) {
      asm volatile("s_waitcnt vmcnt(6)" ::: "memory");  // own tile-t loads landed
    } else {
      asm volatile("s_waitcnt vmcnt(0)" ::: "memory");
    }
    __builtin_amdgcn_s_barrier();          // all waves' tile-t loads landed
    __builtin_amdgcn_sched_barrier(0);     // nothing hoists above the barrier
    const char* Aq = (const char*)lds + q * 49152;
    const int q2 = (q == 0) ? 2 : q - 1;   // buffer for tile t+2

    bf16x8 a0[4], b0[4], a1[4], b1[4];
#pragma unroll
    for (int m = 0; m < 4; ++m) a0[m] = *(const bf16x8*)(Aq + aRow + m * 2048 + x0);
#pragma unroll
    for (int n = 0; n < 4; ++n) b0[n] = *(const bf16x8*)(Aq + bRow + n * 2048 + x0);
#pragma unroll
    for (int m = 0; m < 4; ++m) a1[m] = *(const bf16x8*)(Aq + aRow + m * 2048 + x1);
#pragma unroll
    for (int n = 0; n < 4; ++n) b1[n] = *(const bf16x8*)(Aq + bRow + n * 2048 + x1);

    if (t < 30) {
      STG_A(q2, t + 2, 0); STG_A(q2, t + 2, 1); STG_A(q2, t + 2, 2); STG_A(q2, t + 2, 3);
      STG_B(q2, t + 2, 0); STG_B(q2, t + 2, 1);
    }

    __builtin_amdgcn_s_setprio(1);
#pragma unroll
    for (int m = 0; m < 4; ++m)
#pragma unroll
      for (int n = 0; n < 4; ++n) acc[m][n] = MFMA16(a0[m], b0[n], acc[m][n]);
#pragma unroll
    for (int m = 0; m < 4; ++m)
#pragma unroll
      for (int n = 0; n < 4; ++n) acc[m][n] = MFMA16(a1[m], b1[n], acc[m][n]);
    __builtin_amdgcn_s_setprio(0);
    q = (q == 2) ? 0 : q + 1;
  }
#undef STG_A
#undef STG_B

  // ---- epilogue ----
  if constexpr (MODE == 2) {
    const int sect = bn >> 11;  // 0=Q, 1=K, 2=V (buffers 16MB apart = 8388608 u16)
    u16* Cq = (u16*)Cv + (size_t)sect * 8388608;
    const int cb = (bn & 2047) + wc * 64;
    if (sect < 2) {
      // fused RoPE: lane pairs (lo16^1) hold the (even,odd) column pair.
      // __sinf/__cosf (value-returning, v_sin/v_cos) -- NO sincosf (scratch spill, round-8 lesson).
      const float qsc = (sect == 0) ? 0.08838834764831845f : 1.0f;
      float freq[4];
#pragma unroll
      for (int n = 0; n < 4; ++n) {
        const int c = cb + n * 16 + lo16;
        freq[n] = exp2f((float)((c & 127) >> 1) * -0.2076205059304601f);
      }
      const float sg = (lo16 & 1) ? 1.f : -1.f;  // cb, n*16 are even
#pragma unroll
      for (int m = 0; m < 4; ++m) {
        const int row = bm + wr * 64 + m * 16 + hi * 4;
#pragma unroll
        for (int r = 0; r < 4; ++r) {
          const float p = (float)pos[row + r];
#pragma unroll
          for (int n = 0; n < 4; ++n) {
            const float ang = p * freq[n];
            const float sn = __sinf(ang);
            const float cs = __cosf(ang);
            const float v = acc[m][n][r];
            const float pv = __shfl_xor(v, 1);
            Cq[(size_t)(row + r) * 2048 + cb + n * 16 + lo16] =
                f2bf((v * cs + sg * pv * sn) * qsc);
          }
        }
      }
    } else {
#pragma unroll
      for (int m = 0; m < 4; ++m)
#pragma unroll
        for (int n = 0; n < 4; ++n)
#pragma unroll
          for (int r = 0; r < 4; ++r)
            Cq[(size_t)(bm + wr * 64 + m * 16 + hi * 4 + r) * 2048 + cb + n * 16 + lo16] =
                f2bf(acc[m][n][r]);
    }
  } else {
    float* C = (float*)Cv;
    const int cb = bn + wc * 64;
#pragma unroll
    for (int m = 0; m < 4; ++m)
#pragma unroll
      for (int n = 0; n < 4; ++n)
#pragma unroll
        for (int r = 0; r < 4; ++r)
          C[(size_t)(bm + wr * 64 + m * 16 + hi * 4 + r) * 2048 + cb + n * 16 + lo16] =
              acc[m][n][r];
  }
}

// ------------- causal flash attention v4: QTILE=64 (4 waves x 16 rows), KVBLK=64 -------------
// Each block processes TWO complementary q-tiles (31-pairid, then pairid) => exactly 33
// KV-steps per block, balance independent of block->CU mapping. Double-buffered K/V staging.
__global__ __launch_bounds__(256, 2) void flash_attn4(const u16* __restrict__ Qb,
                                                      const u16* __restrict__ Kb,
                                                      const u16* __restrict__ VT,
                                                      u16* __restrict__ Ob) {
  constexpr int S = 2048, HD = 2048;
  const int g = (int)blockIdx.x;
  const int xcd = g & 7, slot = g >> 3;      // 64 slots per XCD
  const int bh = xcd * 4 + (slot & 3);       // 4 heads per XCD (K/V ~2MB -> L2 resident)
  const int pairid = slot >> 2;              // 0..15
  const int b = bh >> 4, h = bh & 15;
  const int tid = threadIdx.x, lane = tid & 63, wid = tid >> 6;

  __shared__ u16 Ks[2][64 * 128];   // [kv][d] swizzled, double-buffered (32KB)
  __shared__ u16 Vs[2][128 * 64];   // [d][kv] swizzled, double-buffered (32KB)
  __shared__ u16 Ps[4][16 * 64];    // per-wave P [q][kv], swizzled (8KB)

  const size_t base = (size_t)b * S * HD + (size_t)h * 128;
  const u16* Qp = Qb + base;
  const u16* Kp = Kb + base;
  const u16* VTp = VT + (size_t)bh * 128 * S;
  u16* Op = Ob + base;

  const f32x4 z4 = {0.f, 0.f, 0.f, 0.f};
  const int kKv = (lane >> 4);
  const int kC16 = (lane & 15);
  const int vD = (lane >> 3);
  const int vC16 = (lane & 7);

#define STAGE(pb, kv0_)                                                                   \
  {                                                                                       \
    _Pragma("unroll") for (int c = 0; c < 4; ++c) {                                       \
      const int ch = wid * 4 + c;                                                         \
      {                                                                                   \
        const int kv = ch * 4 + kKv;                                                      \
        const int c16 = kC16 ^ (kv & 7);                                                  \
        gload16(Kp + (size_t)((kv0_) + kv) * HD + c16 * 8, (char*)Ks[pb] + ch * 1024);    \
      }                                                                                   \
      {                                                                                   \
        const int d = ch * 8 + vD;                                                        \
        const int c16 = vC16 ^ (d & 7);                                                   \
        gload16(VTp + (size_t)d * S + (kv0_) + c16 * 8, (char*)Vs[pb] + ch * 1024);       \
      }                                                                                   \
    }                                                                                     \
  }

#pragma unroll
  for (int half = 0; half < 2; ++half) {
    const int qt = half ? pairid : 31 - pairid;  // heavy tile first
    const int q0 = qt * 64;

    bf16x8 qf[4];
    {
      const int qr = q0 + wid * 16 + (lane & 15);
      const int kc = (lane >> 4) * 8;
#pragma unroll
      for (int kb = 0; kb < 4; ++kb)
        qf[kb] = *(const bf16x8*)(Qp + (size_t)qr * HD + kb * 32 + kc);
    }

    f32x4 accO[8];
#pragma unroll
    for (int d = 0; d < 8; ++d) accO[d] = z4;
    float m_r[4] = {-INFINITY, -INFINITY, -INFINITY, -INFINITY};
    float l_r[4] = {0.f, 0.f, 0.f, 0.f};

    STAGE(0, 0);
    __syncthreads();  // buffer 0 ready (drains vmcnt)

    for (int t = 0; t <= qt; ++t) {
      const int cur = t & 1;
      const int kv0 = t * 64;
      if (t < qt) STAGE(cur ^ 1, kv0 + 64);  // prefetch next tile into other buffer

      const u16* Ksc = Ks[cur];
      const u16* Vsc = Vs[cur];
      f32x4 accS[4];
#pragma unroll
      for (int nb = 0; nb < 4; ++nb) accS[nb] = z4;

      // ---- S = Q K^T ----
      __builtin_amdgcn_s_setprio(1);
#pragma unroll
      for (int nb = 0; nb < 4; ++nb) {
        const int kv = nb * 16 + (lane & 15);
#pragma unroll
        for (int kb = 0; kb < 4; ++kb) {
          const int c16 = (kb * 4 + (lane >> 4)) ^ (kv & 7);
          bf16x8 kf = *(const bf16x8*)((char*)Ksc + kv * 256 + c16 * 16);
          accS[nb] = MFMA16(qf[kb], kf, accS[nb]);
        }
      }
      __builtin_amdgcn_s_setprio(0);

      // ---- causal mask (diagonal step only) ----
      if (t == qt) {
#pragma unroll
        for (int nb = 0; nb < 4; ++nb) {
          const int kv = kv0 + nb * 16 + (lane & 15);
          const int qrow = q0 + wid * 16 + (lane >> 4) * 4;
#pragma unroll
          for (int j = 0; j < 4; ++j)
            if (kv > qrow + j) accS[nb][j] = -INFINITY;
        }
      }

      // ---- online softmax (row = (lane>>4)*4+j) + P write ----
      u16* Pw = &Ps[wid][0];
#pragma unroll
      for (int j = 0; j < 4; ++j) {
        float mx = fmaxf(fmaxf(accS[0][j], accS[1][j]), fmaxf(accS[2][j], accS[3][j]));
#pragma unroll
        for (int off = 1; off < 16; off <<= 1) mx = fmaxf(mx, __shfl_xor(mx, off));
        const float mn = fmaxf(m_r[j], mx);
        const float sc = __expf(m_r[j] - mn);
        m_r[j] = mn;
        float s = 0.f;
#pragma unroll
        for (int nb = 0; nb < 4; ++nb) {
          const float p = __expf(accS[nb][j] - mn);
          accS[nb][j] = p;
          s += p;
        }
#pragma unroll
        for (int off = 1; off < 16; off <<= 1) s += __shfl_xor(s, off);
        l_r[j] = l_r[j] * sc + s;
#pragma unroll
        for (int db = 0; db < 8; ++db) accO[db][j] *= sc;
        const int ql = (lane >> 4) * 4 + j;
#pragma unroll
        for (int nb = 0; nb < 4; ++nb) {
          const int col = nb * 16 + (lane & 15);
          const int byteoff = ql * 128 + ((((col >> 3) ^ (ql & 7))) << 4) + (col & 7) * 2;
          *(u16*)((char*)Pw + byteoff) = f2bf(accS[nb][j]);
        }
      }

      // ---- O += P V ----
#pragma unroll
      for (int kb2 = 0; kb2 < 2; ++kb2) {
        const int ql = lane & 15;
        const int c16a = (kb2 * 4 + (lane >> 4)) ^ (ql & 7);
        bf16x8 pa = *(const bf16x8*)((char*)Pw + ql * 128 + c16a * 16);
        __builtin_amdgcn_s_setprio(1);
#pragma unroll
        for (int db = 0; db < 8; ++db) {
          const int d = db * 16 + (lane & 15);
          const int c16 = (kb2 * 4 + (lane >> 4)) ^ (d & 7);
          bf16x8 vf = *(const bf16x8*)((char*)Vsc + d * 128 + c16 * 16);
          accO[db] = MFMA16(pa, vf, accO[db]);
        }
        __builtin_amdgcn_s_setprio(0);
      }
      __syncthreads();  // prefetch landed during compute; LDS reads of this step done
    }

    // ---- epilogue: normalize, store bf16 ----
    float inv[4];
#pragma unroll
    for (int j = 0; j < 4; ++j) inv[j] = 1.f / l_r[j];
#pragma unroll
    for (int db = 0; db < 8; ++db)
#pragma unroll
      for (int j = 0; j < 4; ++j) {
        const int row = q0 + wid * 16 + (lane >> 4) * 4 + j;
        Op[(size_t)row * HD + db * 16 + (lane & 15)] = f2bf(accO[db][j] * inv[j]);
      }
  }
#undef STAGE
}

extern "C" void kernel_launch(void* const* d_in, const int* in_sizes, int n_in,
                              void* d_out, int out_size, void* d_ws, size_t ws_size,
                              hipStream_t stream) {
  const float* x  = (const float*)d_in[0];
  const int*   tp = (const int*)d_in[1];
  const float* WQ = (const float*)d_in[2];
  const float* WK = (const float*)d_in[3];
  const float* WV = (const float*)d_in[4];
  const float* WO = (const float*)d_in[5];

  const size_t MB = 1024 * 1024;
  if (ws_size < 112 * MB) return;
  char* ws = (char*)d_ws;
  u16* xb  = (u16*)(ws + 0 * MB);
  u16* wqt = (u16*)(ws + 16 * MB);   // wqt/wkt/wvt/wot contiguous, 8MB each
  u16* wot = (u16*)(ws + 40 * MB);
  u16* Qb  = (u16*)(ws + 48 * MB);   // Qb/Kb/Vb contiguous, 16MB apart
  u16* Kb  = (u16*)(ws + 64 * MB);
  u16* Vb  = (u16*)(ws + 80 * MB);
  u16* Obf = (u16*)(ws + 96 * MB);
  u16* VTb = xb;  // V^T [B,H,dk,S] (xb dead after projections)

  cvt_f32_to_bf16<<<8192, 256, 0, stream>>>(x, xb, 2097152);
  {
    dim3 g(64, 64, 4), blk(32, 8);
    transpose_cvt4<<<g, blk, 0, stream>>>(WQ, WK, WV, WO, wqt);
  }
  // fused QKV projection + RoPE: [4096][2048] x [6144][2048]^T -> Qb|Kb|Vb
  gemm8<2><<<768, 512, 0, stream>>>(xb, wqt, (void*)Qb, tp, 48);

  {
    dim3 g(64, 128), blk(32, 8);
    vtrans<<<g, blk, 0, stream>>>(Vb, VTb);
  }
  flash_attn4<<<512, 256, 0, stream>>>(Qb, Kb, VTb, Obf);

  // output projection -> f32 d_out
  gemm8<1><<<256, 512, 0, stream>>>(Obf, wot, d_out, nullptr, 16);
}